// Round 3
// baseline (212.185 us; speedup 1.0000x reference)
//
#include <hip/hip_runtime.h>

#define HW_ (256 * 256)

// One wave (64 threads) handles one (window, head) unit.
// Block = 256 threads = 4 units sharing the same (b, h, wn), wm = 4 consecutive.
// Thread t = query row (token) within the window; s[64] = its score row.
__global__ __launch_bounds__(256, 4)
void slice_attn_kernel(const float* __restrict__ Q,
                       const float* __restrict__ K,
                       const float* __restrict__ V,
                       const float* __restrict__ RT,
                       float* __restrict__ O) {
  __shared__ __align__(16) float k_lds[4][1024];  // [unit][kt*16 + cc]
  __shared__ __align__(16) float v_lds[4][1024];
  __shared__ float bias_lds[225];                 // rel-pos column for this head

  const int tid  = threadIdx.x;
  const int wave = tid >> 6;
  const int t    = tid & 63;
  const int bid  = blockIdx.x;

  // unit u = bid*4 + wave; decode (b, h, wn, wm) with wm innermost for L2 locality
  const int wm = ((bid & 7) << 2) | wave;
  const int wn = (bid >> 3) & 31;
  const int h  = (bid >> 8) & 7;
  const int b  = bid >> 11;

  // stage bias column for head h (shared by all 4 waves in the block)
  if (tid < 225) bias_lds[tid] = RT[tid * 8 + h];

  const int sh = t >> 3, sw = t & 7;
  const int y  = wn * 8 + sh;
  const int x  = wm * 8 + sw;
  const int xs = (x - 4) & 255;  // rolled-right-by-4 source column (wraps at wm==0)

  const int base = (b * 128 + h * 16) * HW_;
  const float* qp = Q + base + y * 256 + x;
  const float* kp = K + base + y * 256 + xs;
  const float* vp = V + base + y * 256 + xs;

  float* kl = k_lds[wave];
  float* vl = v_lds[wave];

  float qr[16];
  #pragma unroll
  for (int c4 = 0; c4 < 4; ++c4) {
    float4 kv, vv;
    kv.x = kp[(c4 * 4 + 0) * HW_];
    kv.y = kp[(c4 * 4 + 1) * HW_];
    kv.z = kp[(c4 * 4 + 2) * HW_];
    kv.w = kp[(c4 * 4 + 3) * HW_];
    vv.x = vp[(c4 * 4 + 0) * HW_];
    vv.y = vp[(c4 * 4 + 1) * HW_];
    vv.z = vp[(c4 * 4 + 2) * HW_];
    vv.w = vp[(c4 * 4 + 3) * HW_];
    *reinterpret_cast<float4*>(kl + t * 16 + c4 * 4) = kv;
    *reinterpret_cast<float4*>(vl + t * 16 + c4 * 4) = vv;
    // q * SCALE (0.25 is a power of 2 -> exact)
    qr[c4 * 4 + 0] = qp[(c4 * 4 + 0) * HW_] * 0.25f;
    qr[c4 * 4 + 1] = qp[(c4 * 4 + 1) * HW_] * 0.25f;
    qr[c4 * 4 + 2] = qp[(c4 * 4 + 2) * HW_] * 0.25f;
    qr[c4 * 4 + 3] = qp[(c4 * 4 + 3) * HW_] * 0.25f;
  }
  __syncthreads();

  // ---- scores: bit-replicate numpy einsum's f32 sum-of-products
  //      (SSE 4-lane accumulator, NO fma, lane_j = ((p_j+p_{j+4})+p_{j+8})+p_{j+12},
  //       horizontal reduce (L0+L1)+(L2+L3)) — so our top-k boundary decisions
  //      match the np reference's bit-for-bit.
  float s[64];
  {
    #pragma clang fp contract(off)
    #pragma unroll
    for (int kt = 0; kt < 64; ++kt) {
      const float4* kr = reinterpret_cast<const float4*>(kl + kt * 16);
      const float4 k0 = kr[0], k1 = kr[1], k2 = kr[2], k3 = kr[3];
      const float p0  = qr[0]  * k0.x;
      const float p1  = qr[1]  * k0.y;
      const float p2  = qr[2]  * k0.z;
      const float p3  = qr[3]  * k0.w;
      const float p4  = qr[4]  * k1.x;
      const float p5  = qr[5]  * k1.y;
      const float p6  = qr[6]  * k1.z;
      const float p7  = qr[7]  * k1.w;
      const float p8  = qr[8]  * k2.x;
      const float p9  = qr[9]  * k2.y;
      const float p10 = qr[10] * k2.z;
      const float p11 = qr[11] * k2.w;
      const float p12 = qr[12] * k3.x;
      const float p13 = qr[13] * k3.y;
      const float p14 = qr[14] * k3.z;
      const float p15 = qr[15] * k3.w;
      const float L0 = ((p0 + p4) + p8)  + p12;
      const float L1 = ((p1 + p5) + p9)  + p13;
      const float L2 = ((p2 + p6) + p10) + p14;
      const float L3 = ((p3 + p7) + p11) + p15;
      s[kt] = (L0 + L1) + (L2 + L3);
    }
  }

  // ---- top-16: 16 extract-max rounds, FIRST-index-only knockout
  //      (matches top_k tie semantics: exactly 16, lowest index wins)
  #pragma unroll 1
  for (int r = 0; r < 16; ++r) {
    float tmp[32];
    #pragma unroll
    for (int i = 0; i < 32; ++i) tmp[i] = fmaxf(s[i], s[i + 32]);
    #pragma unroll
    for (int wdt = 16; wdt >= 1; wdt >>= 1) {
      #pragma unroll
      for (int i = 0; i < wdt; ++i) tmp[i] = fmaxf(tmp[i], tmp[i + wdt]);
    }
    const float mv  = tmp[0];
    const float kv2 = mv - 1024.0f;  // knocked marker, < -512 always
    bool taken = false;
    #pragma unroll
    for (int i = 0; i < 64; ++i) {
      const bool hit = (!taken) && (s[i] == mv);
      s[i] = hit ? kv2 : s[i];
      taken = taken || hit;
    }
  }

  // ---- recover originals (±6e-5 restore error, harmless), record selection, add bias
  const int vbase = sh * 15 + sw;  // ridx = vbase + (112 - kh*15 - kw), always >= 0
  const float* bp = &bias_lds[vbase];
  unsigned selLo = 0u, selHi = 0u;
  #pragma unroll
  for (int i = 0; i < 64; ++i) {
    const float bv  = bp[112 - (i >> 3) * 15 - (i & 7)];
    const bool sel  = s[i] < -512.0f;              // |true score| << 512
    const float orig = sel ? s[i] + 1024.0f : s[i];
    s[i] = orig + bv;
    if (i < 32) selLo |= sel ? (1u << i) : 0u;
    else        selHi |= sel ? (1u << (i - 32)) : 0u;
  }

  // ---- softmax over all 64 (mask & knn applied AFTER, per reference)
  {
    float tmp[32];
    #pragma unroll
    for (int i = 0; i < 32; ++i) tmp[i] = fmaxf(s[i], s[i + 32]);
    #pragma unroll
    for (int wdt = 16; wdt >= 1; wdt >>= 1) {
      #pragma unroll
      for (int i = 0; i < wdt; ++i) tmp[i] = fmaxf(tmp[i], tmp[i + wdt]);
    }
    const float m = tmp[0];
    float d0 = 0.f, d1 = 0.f, d2 = 0.f, d3 = 0.f;
    #pragma unroll
    for (int i = 0; i < 64; i += 4) {
      const float p0 = __expf(s[i] - m);
      const float p1 = __expf(s[i + 1] - m);
      const float p2 = __expf(s[i + 2] - m);
      const float p3 = __expf(s[i + 3] - m);
      s[i] = p0; s[i + 1] = p1; s[i + 2] = p2; s[i + 3] = p3;
      d0 += p0; d1 += p1; d2 += p2; d3 += p3;
    }
    const float denom = (d0 + d1) + (d2 + d3);
    const float inv = 1.0f / denom;
    const bool edge = (wm == 0);
    #pragma unroll
    for (int i = 0; i < 64; ++i) {
      const unsigned bit = (i < 32) ? (selLo >> i) : (selHi >> (i - 32));
      float w = (bit & 1u) ? s[i] * inv : 0.0f;
      if (edge && (i & 7) < 4) w = 0.0f;  // post-softmax column mask
      s[i] = w;
    }
  }

  // ---- PV: out[cc] = sum_kt w[kt] * v[kt][cc]
  float acc[16];
  #pragma unroll
  for (int cc = 0; cc < 16; ++cc) acc[cc] = 0.0f;
  #pragma unroll
  for (int kt = 0; kt < 64; ++kt) {
    const float w = s[kt];
    const float4* vr = reinterpret_cast<const float4*>(vl + kt * 16);
    const float4 v0 = vr[0], v1 = vr[1], v2 = vr[2], v3 = vr[3];
    acc[0]  += w * v0.x; acc[1]  += w * v0.y; acc[2]  += w * v0.z; acc[3]  += w * v0.w;
    acc[4]  += w * v1.x; acc[5]  += w * v1.y; acc[6]  += w * v1.z; acc[7]  += w * v1.w;
    acc[8]  += w * v2.x; acc[9]  += w * v2.y; acc[10] += w * v2.z; acc[11] += w * v2.w;
    acc[12] += w * v3.x; acc[13] += w * v3.y; acc[14] += w * v3.z; acc[15] += w * v3.w;
  }

  // ---- store
  float* op = O + base + y * 256 + x;
  #pragma unroll
  for (int cc = 0; cc < 16; ++cc) op[cc * HW_] = acc[cc];
}

extern "C" void kernel_launch(void* const* d_in, const int* in_sizes, int n_in,
                              void* d_out, int out_size, void* d_ws, size_t ws_size,
                              hipStream_t stream) {
  const float* Q  = (const float*)d_in[0];
  const float* K  = (const float*)d_in[1];
  const float* V  = (const float*)d_in[2];
  const float* RT = (const float*)d_in[3];
  float* O = (float*)d_out;
  dim3 grid(4096), block(256);
  hipLaunchKernelGGL(slice_attn_kernel, grid, block, 0, stream, Q, K, V, RT, O);
}

// Round 4
// 200.426 us; speedup vs baseline: 1.0587x; 1.0587x over previous
//
#include <hip/hip_runtime.h>

#define HW_ (256 * 256)

// One wave (64 threads) handles one (window, head) unit.
// Block = 256 threads = 4 units sharing the same (b, h, wn), wm = 4 consecutive.
// Thread t = query row (token) within the window; s[64] = its score row.
__global__ __launch_bounds__(256, 2)
void slice_attn_kernel(const float* __restrict__ Q,
                       const float* __restrict__ K,
                       const float* __restrict__ V,
                       const float* __restrict__ RT,
                       float* __restrict__ O) {
  __shared__ __align__(16) float k_lds[4][1024];  // [unit][kt*16 + cc]
  __shared__ __align__(16) float v_lds[4][1024];
  __shared__ float bias_lds[225];                 // rel-pos column for this head

  const int tid  = threadIdx.x;
  const int wave = tid >> 6;
  const int t    = tid & 63;
  const int bid  = blockIdx.x;

  // unit u = bid*4 + wave; decode (b, h, wn, wm) with wm innermost for L2 locality
  const int wm = ((bid & 7) << 2) | wave;
  const int wn = (bid >> 3) & 31;
  const int h  = (bid >> 8) & 7;
  const int b  = bid >> 11;

  // stage bias column for head h (shared by all 4 waves in the block)
  if (tid < 225) bias_lds[tid] = RT[tid * 8 + h];

  const int sh = t >> 3, sw = t & 7;
  const int y  = wn * 8 + sh;
  const int x  = wm * 8 + sw;
  const int xs = (x - 4) & 255;  // rolled-right-by-4 source column (wraps at wm==0)

  const int base = (b * 128 + h * 16) * HW_;
  const float* qp = Q + base + y * 256 + x;
  const float* kp = K + base + y * 256 + xs;
  const float* vp = V + base + y * 256 + xs;

  float* kl = k_lds[wave];
  float* vl = v_lds[wave];

  float qr[16];
  #pragma unroll
  for (int c4 = 0; c4 < 4; ++c4) {
    float4 kv, vv;
    kv.x = kp[(c4 * 4 + 0) * HW_];
    kv.y = kp[(c4 * 4 + 1) * HW_];
    kv.z = kp[(c4 * 4 + 2) * HW_];
    kv.w = kp[(c4 * 4 + 3) * HW_];
    vv.x = vp[(c4 * 4 + 0) * HW_];
    vv.y = vp[(c4 * 4 + 1) * HW_];
    vv.z = vp[(c4 * 4 + 2) * HW_];
    vv.w = vp[(c4 * 4 + 3) * HW_];
    *reinterpret_cast<float4*>(kl + t * 16 + c4 * 4) = kv;
    *reinterpret_cast<float4*>(vl + t * 16 + c4 * 4) = vv;
    // q * SCALE (0.25 is a power of 2 -> exact)
    qr[c4 * 4 + 0] = qp[(c4 * 4 + 0) * HW_] * 0.25f;
    qr[c4 * 4 + 1] = qp[(c4 * 4 + 1) * HW_] * 0.25f;
    qr[c4 * 4 + 2] = qp[(c4 * 4 + 2) * HW_] * 0.25f;
    qr[c4 * 4 + 3] = qp[(c4 * 4 + 3) * HW_] * 0.25f;
  }
  __syncthreads();

  // ---- scores: bit-replicate numpy einsum's f32 sum-of-products
  //      (SSE 4-lane accumulator, NO fma, lane_j = ((p_j+p_{j+4})+p_{j+8})+p_{j+12},
  //       horizontal reduce (L0+L1)+(L2+L3)) — so our top-k boundary decisions
  //      match the np reference's bit-for-bit.
  float s[64];
  {
    #pragma clang fp contract(off)
    #pragma unroll
    for (int kt = 0; kt < 64; ++kt) {
      const float4* kr = reinterpret_cast<const float4*>(kl + kt * 16);
      const float4 k0 = kr[0], k1 = kr[1], k2 = kr[2], k3 = kr[3];
      const float p0  = qr[0]  * k0.x;
      const float p1  = qr[1]  * k0.y;
      const float p2  = qr[2]  * k0.z;
      const float p3  = qr[3]  * k0.w;
      const float p4  = qr[4]  * k1.x;
      const float p5  = qr[5]  * k1.y;
      const float p6  = qr[6]  * k1.z;
      const float p7  = qr[7]  * k1.w;
      const float p8  = qr[8]  * k2.x;
      const float p9  = qr[9]  * k2.y;
      const float p10 = qr[10] * k2.z;
      const float p11 = qr[11] * k2.w;
      const float p12 = qr[12] * k3.x;
      const float p13 = qr[13] * k3.y;
      const float p14 = qr[14] * k3.z;
      const float p15 = qr[15] * k3.w;
      const float L0 = ((p0 + p4) + p8)  + p12;
      const float L1 = ((p1 + p5) + p9)  + p13;
      const float L2 = ((p2 + p6) + p10) + p14;
      const float L3 = ((p3 + p7) + p11) + p15;
      s[kt] = (L0 + L1) + (L2 + L3);
    }
  }

  // ---- threshold via full bitonic sort (ascending) of a value copy.
  //      672 compare-exchanges, all indices compile-time -> registers.
  float c[64];
  #pragma unroll
  for (int i = 0; i < 64; ++i) c[i] = s[i];
  #pragma unroll
  for (int k = 2; k <= 64; k <<= 1) {
    #pragma unroll
    for (int j = k >> 1; j > 0; j >>= 1) {
      #pragma unroll
      for (int i = 0; i < 64; ++i) {
        const int l = i ^ j;
        if (l > i) {
          const bool up = ((i & k) == 0);
          const float a = c[i], bb = c[l];
          const float mn = fminf(a, bb), mx = fmaxf(a, bb);
          c[i] = up ? mn : mx;
          c[l] = up ? mx : mn;
        }
      }
    }
  }
  const float thr = c[48];   // 16th largest
  const float m   = c[63];   // max (pre-bias; bias |.|<=~0.1, exp arg <= ~0.12: safe)

  // ---- selection: all > thr, plus == thr lowest-index-first until 16 total
  //      (matches top_k tie semantics exactly)
  int cgt = 0;
  #pragma unroll
  for (int i = 0; i < 64; ++i) cgt += (s[i] > thr) ? 1 : 0;
  unsigned selLo = 0u, selHi = 0u;
  {
    int cnt = cgt;
    #pragma unroll
    for (int i = 0; i < 64; ++i) {
      const bool eq   = (s[i] == thr);
      const bool take = (s[i] > thr) || (eq && (cnt < 16));
      cnt += eq ? 1 : 0;
      if (i < 32) selLo |= take ? (1u << i) : 0u;
      else        selHi |= take ? (1u << (i - 32)) : 0u;
    }
  }

  // ---- bias + softmax over all 64 (mask & knn applied AFTER, per reference)
  const int vbase = sh * 15 + sw;  // ridx = vbase + (112 - kh*15 - kw), always >= 0
  const float* bp = &bias_lds[vbase];
  {
    float d0 = 0.f, d1 = 0.f, d2 = 0.f, d3 = 0.f;
    #pragma unroll
    for (int i = 0; i < 64; i += 4) {
      const float b0 = bp[112 - ((i + 0) >> 3) * 15 - ((i + 0) & 7)];
      const float b1 = bp[112 - ((i + 1) >> 3) * 15 - ((i + 1) & 7)];
      const float b2 = bp[112 - ((i + 2) >> 3) * 15 - ((i + 2) & 7)];
      const float b3 = bp[112 - ((i + 3) >> 3) * 15 - ((i + 3) & 7)];
      const float p0 = __expf(s[i + 0] + b0 - m);
      const float p1 = __expf(s[i + 1] + b1 - m);
      const float p2 = __expf(s[i + 2] + b2 - m);
      const float p3 = __expf(s[i + 3] + b3 - m);
      s[i] = p0; s[i + 1] = p1; s[i + 2] = p2; s[i + 3] = p3;
      d0 += p0; d1 += p1; d2 += p2; d3 += p3;
    }
    const float denom = (d0 + d1) + (d2 + d3);
    const float inv = 1.0f / denom;
    const bool edge = (wm == 0);
    #pragma unroll
    for (int i = 0; i < 64; ++i) {
      const unsigned bit = (i < 32) ? (selLo >> i) : (selHi >> (i - 32));
      float w = (bit & 1u) ? s[i] * inv : 0.0f;
      if (edge && (i & 7) < 4) w = 0.0f;  // post-softmax column mask
      s[i] = w;
    }
  }

  // ---- PV: out[cc] = sum_kt w[kt] * v[kt][cc]
  float acc[16];
  #pragma unroll
  for (int cc = 0; cc < 16; ++cc) acc[cc] = 0.0f;
  #pragma unroll
  for (int kt = 0; kt < 64; ++kt) {
    const float w = s[kt];
    const float4* vr = reinterpret_cast<const float4*>(vl + kt * 16);
    const float4 v0 = vr[0], v1 = vr[1], v2 = vr[2], v3 = vr[3];
    acc[0]  += w * v0.x; acc[1]  += w * v0.y; acc[2]  += w * v0.z; acc[3]  += w * v0.w;
    acc[4]  += w * v1.x; acc[5]  += w * v1.y; acc[6]  += w * v1.z; acc[7]  += w * v1.w;
    acc[8]  += w * v2.x; acc[9]  += w * v2.y; acc[10] += w * v2.z; acc[11] += w * v2.w;
    acc[12] += w * v3.x; acc[13] += w * v3.y; acc[14] += w * v3.z; acc[15] += w * v3.w;
  }

  // ---- store
  float* op = O + base + y * 256 + x;
  #pragma unroll
  for (int cc = 0; cc < 16; ++cc) op[cc * HW_] = acc[cc];
}

extern "C" void kernel_launch(void* const* d_in, const int* in_sizes, int n_in,
                              void* d_out, int out_size, void* d_ws, size_t ws_size,
                              hipStream_t stream) {
  const float* Q  = (const float*)d_in[0];
  const float* K  = (const float*)d_in[1];
  const float* V  = (const float*)d_in[2];
  const float* RT = (const float*)d_in[3];
  float* O = (float*)d_out;
  dim3 grid(4096), block(256);
  hipLaunchKernelGGL(slice_attn_kernel, grid, block, 0, stream, Q, K, V, RT, O);
}